// Round 2
// baseline (92.544 us; speedup 1.0000x reference)
//
#include <hip/hip_runtime.h>

// 4-qubit, 2-layer QML circuit, B=1M samples.
// One thread computes TWO samples (stage-interleaved for ILP — the
// butterfly stages are serial FMA chains; two independent streams per
// wave hide the 4-cyc dependent-ALU latency that a single stream can't).
//
// Weight-only constants precomputed into d_ws (40 floats) by a tiny
// kernel: uniform-address loads in the main kernel become s_loads ->
// SGPRs (round-1 experiment proved per-thread weight trig costs ~3 us).
//
// ALGEBRAIC REDUCTION: the four layer-2 RZ gates are provably dead —
// RZ is diagonal, the following CNOT chain is a basis permutation, and
// the output is |amp|^2, which kills all per-basis-state phases.
// Layer-2 gate is therefore U = RY(wy)*RX(x), an SU(2) matrix
//   U = [[al, be], [-conj(be), conj(al)]]
//   al = (cy*c,  sy*s),  be = (-sy*c, -cy*s)
// built with 4 mults per qubit (was 16 FMAs).
//
// Flat amp index n = q0*8 + q1*4 + q2*2 + q3 (qubit 0 = bit 3).
//
// Per-sample trig: x in [0, 2pi) -> sin(x/2) = v_sin(x/(4pi)), no range
// reduction needed (rev in [0, 0.5)).

struct C2 { float r, i; };

__device__ __forceinline__ C2 cmul(C2 a, C2 b) {
    C2 o;
    o.r = a.r * b.r - a.i * b.i;
    o.i = a.r * b.i + a.i * b.r;
    return o;
}

#define INV_4PI 0.07957747154594767f

// ---- precompute weight-only gate constants ----
// g[0..31]:  l=0 qubit q: g[q*8 + 0..7] = Pr,Pi,Qr,Qi,Rr,Ri,Sr,Si
// g[32..39]: l=1 qubit q: g[32 + q*2 + {0,1}] = cos(wy/2), sin(wy/2)
__global__ void precompute_gates(const float* __restrict__ w, float* __restrict__ g) {
    int t = threadIdx.x;  // 0..7 -> l*4 + q
    if (t >= 8) return;
    int l = t >> 2, q = t & 3;
    if (l == 0) {
        float thy = w[q * 2 + 0];
        float thz = w[q * 2 + 1];
        float cy = cosf(0.5f * thy), sy = sinf(0.5f * thy);
        float cz = cosf(0.5f * thz), sz = sinf(0.5f * thz);
        float* o = g + q * 8;
        // v0 = c*P + s*Q ; v1 = c*R + s*S  (RZ*RY*RX|0>)
        o[0] = cz * cy;  o[1] = -sz * cy;
        o[2] = sz * sy;  o[3] =  cz * sy;
        o[4] = cz * sy;  o[5] =  sz * sy;
        o[6] = sz * cy;  o[7] = -cz * cy;
    } else {
        float thy = w[8 + q * 2 + 0];  // layer-2 RZ (w[8+q*2+1]) is dead
        g[32 + q * 2 + 0] = cosf(0.5f * thy);
        g[32 + q * 2 + 1] = sinf(0.5f * thy);
    }
}

__device__ __forceinline__ void cnot_chain(C2 st[16]) {
    // CNOT(0,1): q0=1 -> flip q1: swap n=8..11 <-> 12..15
    #pragma unroll
    for (int j = 0; j < 4; j++) { C2 t = st[8 + j]; st[8 + j] = st[12 + j]; st[12 + j] = t; }
    // CNOT(1,2): q1=1 -> flip q2
    {
        C2 t;
        t = st[4];  st[4]  = st[6];  st[6]  = t;
        t = st[5];  st[5]  = st[7];  st[7]  = t;
        t = st[12]; st[12] = st[14]; st[14] = t;
        t = st[13]; st[13] = st[15]; st[15] = t;
    }
    // CNOT(2,3): q2=1 -> flip q3
    {
        C2 t;
        t = st[2];  st[2]  = st[3];  st[3]  = t;
        t = st[6];  st[6]  = st[7];  st[7]  = t;
        t = st[10]; st[10] = st[11]; st[11] = t;
        t = st[14]; st[14] = st[15]; st[15] = t;
    }
}

__global__ void __launch_bounds__(256) qml_kernel(
        const float* __restrict__ x, const float* __restrict__ g,
        float* __restrict__ out, int batch) {
    int base = (blockIdx.x * blockDim.x + threadIdx.x) * 2;
    if (base >= batch) return;
    int idx1 = (base + 1 < batch) ? base + 1 : base;  // tail: duplicate (benign)

    // ---- gate constants: uniform loads -> SGPRs ----
    float l1[32];
    #pragma unroll
    for (int j = 0; j < 32; j++) l1[j] = g[j];
    float cb[4], sb[4];
    #pragma unroll
    for (int q = 0; q < 4; q++) { cb[q] = g[32 + q * 2]; sb[q] = g[33 + q * 2]; }

    // ---- per-sample input + trig ----
    float4 xv[2];
    xv[0] = reinterpret_cast<const float4*>(x)[base];
    xv[1] = reinterpret_cast<const float4*>(x)[idx1];

    float c[2][4], s[2][4];
    #pragma unroll
    for (int k = 0; k < 2; k++) {
        float xs0 = xv[k].x, xs1 = xv[k].y, xs2 = xv[k].z, xs3 = xv[k].w;
        float r0 = xs0 * INV_4PI, r1 = xs1 * INV_4PI, r2 = xs2 * INV_4PI, r3 = xs3 * INV_4PI;
        s[k][0] = __builtin_amdgcn_sinf(r0); c[k][0] = __builtin_amdgcn_cosf(r0);
        s[k][1] = __builtin_amdgcn_sinf(r1); c[k][1] = __builtin_amdgcn_cosf(r1);
        s[k][2] = __builtin_amdgcn_sinf(r2); c[k][2] = __builtin_amdgcn_cosf(r2);
        s[k][3] = __builtin_amdgcn_sinf(r3); c[k][3] = __builtin_amdgcn_cosf(r3);
    }

    // ---- layer 1: product state, per-qubit 2-vectors ----
    C2 v[2][4][2];
    #pragma unroll
    for (int k = 0; k < 2; k++)
        #pragma unroll
        for (int q = 0; q < 4; q++) {
            const float* o = l1 + q * 8;
            v[k][q][0].r = c[k][q] * o[0] + s[k][q] * o[2];
            v[k][q][0].i = c[k][q] * o[1] + s[k][q] * o[3];
            v[k][q][1].r = c[k][q] * o[4] + s[k][q] * o[6];
            v[k][q][1].i = c[k][q] * o[5] + s[k][q] * o[7];
        }

    // ---- tensor expansion to 16 amps ----
    C2 st[2][16];
    #pragma unroll
    for (int k = 0; k < 2; k++) {
        C2 t01[4], t23[4];
        #pragma unroll
        for (int a = 0; a < 2; a++)
            #pragma unroll
            for (int b = 0; b < 2; b++) {
                t01[a * 2 + b] = cmul(v[k][0][a], v[k][1][b]);
                t23[a * 2 + b] = cmul(v[k][2][a], v[k][3][b]);
            }
        #pragma unroll
        for (int a = 0; a < 4; a++)
            #pragma unroll
            for (int b = 0; b < 4; b++)
                st[k][a * 4 + b] = cmul(t01[a], t23[b]);
    }

    #pragma unroll
    for (int k = 0; k < 2; k++) cnot_chain(st[k]);

    // ---- layer 2: SU(2) = RY(wy)*RX(x) per qubit (RZ dropped) ----
    #pragma unroll
    for (int q = 0; q < 4; q++) {
        int bit = 8 >> q;
        #pragma unroll
        for (int k = 0; k < 2; k++) {
            float ar =  cb[q] * c[k][q];
            float ai =  sb[q] * s[k][q];
            float br = -sb[q] * c[k][q];
            float bi = -cb[q] * s[k][q];
            #pragma unroll
            for (int n0 = 0; n0 < 16; n0++) {
                if (n0 & bit) continue;
                int n1 = n0 | bit;
                C2 a0 = st[k][n0], a1 = st[k][n1];
                st[k][n0].r =  ar * a0.r - ai * a0.i + br * a1.r - bi * a1.i;
                st[k][n0].i =  ar * a0.i + ai * a0.r + br * a1.i + bi * a1.r;
                st[k][n1].r = -br * a0.r - bi * a0.i + ar * a1.r + ai * a1.i;
                st[k][n1].i = -br * a0.i + bi * a0.r + ar * a1.i - ai * a1.r;
            }
        }
    }

    #pragma unroll
    for (int k = 0; k < 2; k++) cnot_chain(st[k]);

    // ---- probabilities and <Z_i> ----
    float4 ov[2];
    #pragma unroll
    for (int k = 0; k < 2; k++) {
        float p[16];
        #pragma unroll
        for (int n = 0; n < 16; n++)
            p[n] = st[k][n].r * st[k][n].r + st[k][n].i * st[k][n].i;

        float a8[8], z3 = 0.f;
        #pragma unroll
        for (int m = 0; m < 8; m++) { a8[m] = p[2 * m] + p[2 * m + 1]; z3 += p[2 * m] - p[2 * m + 1]; }
        float b4[4], z2 = 0.f;
        #pragma unroll
        for (int kk = 0; kk < 4; kk++) { b4[kk] = a8[2 * kk] + a8[2 * kk + 1]; z2 += a8[2 * kk] - a8[2 * kk + 1]; }
        float z1 = (b4[0] - b4[1]) + (b4[2] - b4[3]);
        float z0 = (b4[0] + b4[1]) - (b4[2] + b4[3]);
        ov[k] = make_float4(z0, z1, z2, z3);
    }

    reinterpret_cast<float4*>(out)[base] = ov[0];
    reinterpret_cast<float4*>(out)[idx1] = ov[1];
}

extern "C" void kernel_launch(void* const* d_in, const int* in_sizes, int n_in,
                              void* d_out, int out_size, void* d_ws, size_t ws_size,
                              hipStream_t stream) {
    const float* x = (const float*)d_in[0];      // [B,4]
    const float* w = (const float*)d_in[1];      // [2,4,2]
    float* out = (float*)d_out;                  // [B,4]
    float* g = (float*)d_ws;                     // 40 floats of gate constants
    int batch = in_sizes[0] / 4;

    precompute_gates<<<1, 64, 0, stream>>>(w, g);
    int block = 256;
    int threads_needed = (batch + 1) / 2;
    int grid = (threads_needed + block - 1) / block;
    qml_kernel<<<grid, block, 0, stream>>>(x, g, out, batch);
}